// Round 7
// baseline (170.436 us; speedup 1.0000x reference)
//
#include <hip/hip_runtime.h>
#include <hip/hip_bf16.h>
#include <math.h>

#define BATCH 2
#define NSEQ 2048
#define DIM 512
#define HEADS 8
#define DH 64
#define NTOK (BATCH * NSEQ)          // 4096
#define NPROJ (3 * DIM)              // 1536

typedef short short8 __attribute__((ext_vector_type(8)));   // 8 bf16 (4 VGPR)
typedef short short4v __attribute__((ext_vector_type(4)));
typedef float f32x4 __attribute__((ext_vector_type(4)));
typedef float f32x16 __attribute__((ext_vector_type(16)));
typedef __hip_bfloat16 bf16;

static __device__ __forceinline__ short f2b(float f) {
    __hip_bfloat16 h = __float2bfloat16(f);
    return *(short*)&h;
}

static __device__ __forceinline__ void gload_lds16(const void* g, void* l) {
    __builtin_amdgcn_global_load_lds(
        (const __attribute__((address_space(1))) unsigned int*)g,
        (__attribute__((address_space(3))) unsigned int*)l, 16, 0, 0);
}

// ---------------------------------------------------------------------------
// Fused: LayerNorm (blocks 0..4095, one row each) + weight bf16 pack
// (blocks 4096..6143). 128 threads.
// ---------------------------------------------------------------------------
__global__ __launch_bounds__(128) void ln_convert(
    const float* __restrict__ x, const float* __restrict__ gamma,
    const float* __restrict__ beta, bf16* __restrict__ xnb,
    const float* __restrict__ wq1, const float* __restrict__ wk1,
    const float* __restrict__ wv1, const float* __restrict__ wout,
    bf16* __restrict__ Wcat, bf16* __restrict__ woutb)
{
    if (blockIdx.x < NTOK) {
        int row = blockIdx.x;
        int tid = threadIdx.x;
        float4 v = ((const float4*)(x + (size_t)row * DIM))[tid];
        float s  = v.x + v.y + v.z + v.w;
        float s2 = v.x*v.x + v.y*v.y + v.z*v.z + v.w*v.w;
        #pragma unroll
        for (int off = 32; off > 0; off >>= 1) {
            s  += __shfl_down(s,  off);
            s2 += __shfl_down(s2, off);
        }
        __shared__ float red[4];
        if ((tid & 63) == 0) { red[(tid >> 6) * 2] = s; red[(tid >> 6) * 2 + 1] = s2; }
        __syncthreads();
        float S  = red[0] + red[2];
        float S2 = red[1] + red[3];
        float mu  = S * (1.0f / DIM);
        float var = S2 * (1.0f / DIM) - mu * mu;
        float inv = rsqrtf(var + 1e-5f);
        float4 g  = ((const float4*)gamma)[tid];
        float4 be = ((const float4*)beta)[tid];
        short4v o;
        o[0] = f2b((v.x - mu) * inv * g.x + be.x);
        o[1] = f2b((v.y - mu) * inv * g.y + be.y);
        o[2] = f2b((v.z - mu) * inv * g.z + be.z);
        o[3] = f2b((v.w - mu) * inv * g.w + be.w);
        ((short4v*)(xnb + (size_t)row * DIM))[tid] = o;
    } else {
        int i4 = (blockIdx.x - NTOK) * 128 + threadIdx.x;   // 0 .. 262143
        int base = i4 * 4;
        int which = base >> 18;                 // 0..3 (256K elements each)
        int e = base & 262143;
        const float* src = which == 0 ? wq1 : which == 1 ? wk1 : which == 2 ? wv1 : wout;
        float4 v = *(const float4*)(src + e);
        bf16* dst = (which < 3) ? (Wcat + ((size_t)which << 18) + e) : (woutb + e);
        short4v o;
        o[0] = f2b(v.x); o[1] = f2b(v.y); o[2] = f2b(v.z); o[3] = f2b(v.w);
        *(short4v*)dst = o;
    }
}

// ---------------------------------------------------------------------------
// C[m, n] = sum_k A[m, k] * W[n, k]   (bf16 in, fp32 out)
// 128xBN tile, BK=64, 4 waves, 16x16x32 MFMA, 2-phase double-buffered
// global_load_lds pipeline (issue next tile before computing current).
// ---------------------------------------------------------------------------
template<int BN>
__global__ __launch_bounds__(256) void gemm_bf16_nt(
    const bf16* __restrict__ A, const bf16* __restrict__ W,
    float* __restrict__ C, int N, int K)
{
    constexpr int BITS = BN / 32;            // B-stage iterations (and n-frags)
    __shared__ bf16 As[2][128 * 64];
    __shared__ bf16 Bs[2][BN * 64];
    int tid = threadIdx.x;
    int m0 = blockIdx.y * 128, n0 = blockIdx.x * BN;
    int lane = tid & 63;
    int w = tid >> 6;
    int wm = (w >> 1) * 64, wn = (w & 1) * (BN / 2);
    int l15 = lane & 15, l4 = lane >> 4;
    f32x4 acc[4][BITS] = {};

    auto stage = [&](int b, int k0) {
        #pragma unroll
        for (int it = 0; it < 4; it++) {
            int s = it * 256 + tid;
            int row = s >> 3, cs = s & 7;
            gload_lds16(A + (size_t)(m0 + row) * K + k0 + cs * 8, &As[b][s * 8]);
        }
        #pragma unroll
        for (int it = 0; it < BITS; it++) {
            int s = it * 256 + tid;
            int row = s >> 3, cs = s & 7;
            gload_lds16(W + (size_t)(n0 + row) * K + k0 + cs * 8, &Bs[b][s * 8]);
        }
    };

    int NT = K / 64;
    stage(0, 0);
    __syncthreads();
    for (int t = 0; t < NT; ++t) {
        int cur = t & 1;
        if (t + 1 < NT) stage(cur ^ 1, (t + 1) * 64);   // issue-early: overlaps MFMA below
        #pragma unroll
        for (int kk = 0; kk < 64; kk += 32) {
            short8 af[4], bfr[BITS];
            #pragma unroll
            for (int m = 0; m < 4; m++)
                af[m] = *(const short8*)(&As[cur][(wm + m * 16 + l15) * 64 + kk + l4 * 8]);
            #pragma unroll
            for (int n = 0; n < BITS; n++)
                bfr[n] = *(const short8*)(&Bs[cur][(wn + n * 16 + l15) * 64 + kk + l4 * 8]);
            #pragma unroll
            for (int m = 0; m < 4; m++)
                #pragma unroll
                for (int n = 0; n < BITS; n++)
                    acc[m][n] = __builtin_amdgcn_mfma_f32_16x16x32_bf16(
                        af[m], bfr[n], acc[m][n], 0, 0, 0);
        }
        __syncthreads();   // drains next-tile loads (mostly landed under MFMA)
    }
    #pragma unroll
    for (int m = 0; m < 4; m++)
        #pragma unroll
        for (int n = 0; n < BITS; n++) {
            int row = m0 + wm + m * 16 + l4 * 4;
            int col = n0 + wn + n * 16 + l15;
            #pragma unroll
            for (int r = 0; r < 4; r++)
                C[(size_t)(row + r) * N + col] = acc[m][n][r];
        }
}

// ---------------------------------------------------------------------------
// Depthwise causal conv (kernel 3) + head split (+ q scale), bf16 output.
// Vectorized: 4 channels per thread. Reads ycat fp32 [4096][1536].
// ---------------------------------------------------------------------------
__global__ __launch_bounds__(256) void dwconv_kernel(
    const float* __restrict__ ycat,
    const float* __restrict__ wqd, const float* __restrict__ wkd, const float* __restrict__ wvd,
    bf16* __restrict__ q, bf16* __restrict__ k, bf16* __restrict__ v)
{
    int which = blockIdx.z;
    const float* wd = which == 0 ? wqd : which == 1 ? wkd : wvd;
    bf16* dst       = which == 0 ? q   : which == 1 ? k   : v;
    float scale     = which == 0 ? 0.125f : 1.0f;   // DH^-0.5 = 1/8
    int idx = blockIdx.x * 256 + threadIdx.x;       // 0 .. NTOK*128-1
    int e4 = idx & 127;
    int t  = idx >> 7;
    int n  = t & (NSEQ - 1);
    int e  = e4 * 4;
    const float* y = ycat + (size_t)t * NPROJ + which * DIM + e;
    float4 zero = make_float4(0, 0, 0, 0);
    float4 y0 = *(const float4*)y;
    float4 y1 = (n >= 1) ? *(const float4*)(y - NPROJ) : zero;
    float4 y2 = (n >= 2) ? *(const float4*)(y - 2 * NPROJ) : zero;
    const float4* wp = (const float4*)(wd + e * 3);
    float4 wA = wp[0], wB = wp[1], wC = wp[2];
    short4v o;
    o[0] = f2b((wA.x * y2.x + wA.y * y1.x + wA.z * y0.x) * scale);
    o[1] = f2b((wA.w * y2.y + wB.x * y1.y + wB.y * y0.y) * scale);
    o[2] = f2b((wB.z * y2.z + wB.w * y1.z + wC.x * y0.z) * scale);
    o[3] = f2b((wC.y * y2.w + wC.z * y1.w + wC.w * y0.w) * scale);
    int b = t >> 11;
    int h = e >> 6, d = e & 63;
    *(short4v*)(dst + (((size_t)(b * HEADS + h)) * NSEQ + n) * DH + d) = o;
}

// ---------------------------------------------------------------------------
// V transpose: v[bh][n][d] -> vT[bh][d][n]  (bf16). 64x64 tiles via LDS.
// ---------------------------------------------------------------------------
__global__ __launch_bounds__(256) void vtrans_kernel(
    const bf16* __restrict__ v, bf16* __restrict__ vT)
{
    __shared__ unsigned short L[64][72];
    int bh = blockIdx.y;
    int n0 = blockIdx.x * 64;
    int tid = threadIdx.x;
    const unsigned short* src = (const unsigned short*)v + ((size_t)bh * NSEQ + n0) * DH;
    #pragma unroll
    for (int it = 0; it < 2; it++) {
        int idx = it * 256 + tid;
        int r = idx >> 3, c = (idx & 7) * 8;
        *(short8*)&L[r][c] = *(const short8*)(src + (size_t)r * DH + c);
    }
    __syncthreads();
    unsigned short* dst = (unsigned short*)vT + (size_t)bh * DH * NSEQ + n0;
    #pragma unroll
    for (int it = 0; it < 2; it++) {
        int idx = it * 256 + tid;
        int d = idx >> 3, c8 = (idx & 7) * 8;
        short8 o;
        #pragma unroll
        for (int t = 0; t < 8; t++) o[t] = (short)L[c8 + t][d];
        *(short8*)(dst + (size_t)d * NSEQ + c8) = o;
    }
}

// ---------------------------------------------------------------------------
// MFMA flash attention: 4-wave blocks, K-tile shared via double-buffered LDS
// (XOR-swizzled, staged with global_load_lds from pre-swizzled source).
// Wave w owns q-tiles (8tg+2w, 8tg+2w+1); 4-way key split + ALiBi window.
// V stays in per-wave registers (L2-resident; issued early, hidden under QK).
// ---------------------------------------------------------------------------
struct Kf { short8 k[4]; };
struct Vf { short8 v0[2]; short8 v1[2]; };

__device__ __forceinline__ Vf load_v(const unsigned short* __restrict__ vt, int j0, int il, int hi) {
    Vf r;
    #pragma unroll
    for (int jc = 0; jc < 2; jc++) {
        r.v0[jc] = *(const short8*)(vt + (size_t)il * NSEQ + j0 + jc * 16 + hi * 8);
        r.v1[jc] = *(const short8*)(vt + (size_t)(32 + il) * NSEQ + j0 + jc * 16 + hi * 8);
    }
    return r;
}

template<bool MASKED>
__device__ __forceinline__ void tile_step(
    const Kf& kf, const Vf& vf, const short8* qf,
    int j0, int il, int hi, int i_global,
    const float* bconst, float slope2,
    f32x16& o0, f32x16& o1, float& lsum)
{
    f32x16 st = {};
    #pragma unroll
    for (int c = 0; c < 4; c++)
        st = __builtin_amdgcn_mfma_f32_32x32x16_bf16(kf.k[c], qf[c], st, 0, 0, 0);
    float sdb = slope2 * (float)(j0 - i_global);
    float p[16];
    #pragma unroll
    for (int r = 0; r < 16; r++) {
        float e = fmaf(st[r], 1.4426950408889634f, sdb + bconst[r]);
        float pr = exp2f(e);
        if (MASKED) {
            int jl = (r & 3) + 8 * (r >> 2) + 4 * hi;
            pr = (jl <= il) ? pr : 0.0f;
        }
        p[r] = pr;
        lsum += pr;
    }
    unsigned w[8];
    #pragma unroll
    for (int g = 0; g < 4; g++) {
        asm("v_cvt_pk_bf16_f32 %0, %1, %2" : "=v"(w[2*g])   : "v"(p[4*g]),   "v"(p[4*g+1]));
        asm("v_cvt_pk_bf16_f32 %0, %1, %2" : "=v"(w[2*g+1]) : "v"(p[4*g+2]), "v"(p[4*g+3]));
    }
    #pragma unroll
    for (int jc = 0; jc < 2; jc++) {
        unsigned x0 = w[4*jc], x1 = w[4*jc+1], y0 = w[4*jc+2], y1 = w[4*jc+3];
        asm("v_permlane32_swap_b32 %0, %1" : "+v"(x0), "+v"(y0));
        asm("v_permlane32_swap_b32 %0, %1" : "+v"(x1), "+v"(y1));
        union { unsigned u[4]; short8 s; } pa;
        pa.u[0] = x0; pa.u[1] = x1; pa.u[2] = y0; pa.u[3] = y1;
        o0 = __builtin_amdgcn_mfma_f32_32x32x16_bf16(pa.s, vf.v0[jc], o0, 0, 0, 0);
        o1 = __builtin_amdgcn_mfma_f32_32x32x16_bf16(pa.s, vf.v1[jc], o1, 0, 0, 0);
    }
}

__device__ __forceinline__ void write_tile(
    float* __restrict__ po, float* __restrict__ pl,
    int sp, int bh, int i0, int il, int hi,
    const f32x16& o0, const f32x16& o1, float lsum)
{
    float ltot = lsum + __shfl_xor(lsum, 32);
    size_t pbase = ((size_t)sp * (BATCH * HEADS) + bh) * NSEQ + i0;
    if (hi == 0) pl[pbase + il] = ltot;
    float* pop = po + pbase * DH;
    #pragma unroll
    for (int r = 0; r < 16; r++) {
        int irow = (r & 3) + 8 * (r >> 2) + 4 * hi;
        pop[(size_t)irow * DH + il]      = o0[r];
        pop[(size_t)irow * DH + 32 + il] = o1[r];
    }
}

__global__ __launch_bounds__(256) void attn_mfma(
    const bf16* __restrict__ Q, const bf16* __restrict__ K,
    const bf16* __restrict__ VT, float* __restrict__ po, float* __restrict__ pl)
{
    __shared__ bf16 Klds[2][32 * 64];               // 8 KB, double-buffered K tile
    int tg = 7 - blockIdx.x;                        // heavy tile-groups first
    int bh = blockIdx.y;
    int sp = blockIdx.z;                            // key-tile residue 0..3
    int h = bh & (HEADS - 1);
    int tid = threadIdx.x;
    int w = tid >> 6;
    int lane = tid & 63;
    int il = lane & 31, hi = lane >> 5;
    int tiA = 8 * tg + 2 * w, tiB = tiA + 1;
    int i0A = tiA * 32, i0B = i0A + 32;

    float slope2 = exp2f(-(float)(h + 1)) * 1.4426950408889634f;
    float bconst[16];
    #pragma unroll
    for (int r = 0; r < 16; r++) {
        int jl = (r & 3) + 8 * (r >> 2) + 4 * hi;
        bconst[r] = slope2 * (float)jl;
    }
    const bf16* Qb = Q + (size_t)bh * NSEQ * DH;
    const bf16* Kb = K + (size_t)bh * NSEQ * DH;
    const unsigned short* vt = (const unsigned short*)(VT + (size_t)bh * DH * NSEQ);
    short8 qfA[4], qfB[4];
    {
        const short8* qra = (const short8*)(Qb + (size_t)(i0A + il) * DH);
        const short8* qrb = (const short8*)(Qb + (size_t)(i0B + il) * DH);
        #pragma unroll
        for (int c = 0; c < 4; c++) { qfA[c] = qra[2 * c + hi]; qfB[c] = qrb[2 * c + hi]; }
    }
    f32x16 oA0 = {}, oA1 = {}, oB0 = {}, oB1 = {};
    float lsA = 0.0f, lsB = 0.0f;

    // ALiBi window (keys i-j > Wn contribute < e^-20 relative).
    int Wn = 20 << (h + 1);
    // block-uniform loop start (wave 0 has the earliest window):
    int lo0 = (8 * tg * 32 - Wn) >> 5;
    int kt0b = sp;
    if (lo0 > sp) kt0b = sp + (((lo0 - sp) + 3) & ~3);
    // per-wave window start:
    int low = (i0A - Wn) >> 5;
    int ktw = sp;
    if (low > sp) ktw = sp + (((low - sp) + 3) & ~3);
    int KTend = 8 * tg + 7;

    // K stage: LDS dest is linear (tid*16B); global source pre-swizzled so a
    // swizzled ds_read (byte ^= (row&7)<<4) is bank-spread (rule #21).
    auto stageK = [&](int buf, int kt) {
        int row = tid >> 3, slot = tid & 7;
        gload_lds16(Kb + (size_t)(kt * 32 + row) * DH + (slot ^ (row & 7)) * 8,
                    &Klds[buf][tid * 8]);
    };

    stageK(0, kt0b);
    __syncthreads();
    int idx = 0;
    for (int kt = kt0b; kt <= KTend; kt += 4, ++idx) {
        int cur = idx & 1;
        bool active = (kt >= ktw) && (kt <= tiB);
        int j0 = kt * 32;
        Vf vf;
        if (active) vf = load_v(vt, j0, il, hi);    // issue early: hides under QK
        if (kt + 4 <= KTend) stageK(cur ^ 1, kt + 4);
        if (active) {
            Kf kf;
            #pragma unroll
            for (int c = 0; c < 4; c++)
                kf.k[c] = *(const short8*)(
                    &Klds[cur][il * 64 + ((2 * c + hi) ^ (il & 7)) * 8]);
            __builtin_amdgcn_s_setprio(1);
            if (kt < tiA) {
                tile_step<false>(kf, vf, qfA, j0, il, hi, i0A + il, bconst, slope2, oA0, oA1, lsA);
                tile_step<false>(kf, vf, qfB, j0, il, hi, i0B + il, bconst, slope2, oB0, oB1, lsB);
            } else if (kt == tiA) {
                tile_step<true >(kf, vf, qfA, j0, il, hi, i0A + il, bconst, slope2, oA0, oA1, lsA);
                tile_step<false>(kf, vf, qfB, j0, il, hi, i0B + il, bconst, slope2, oB0, oB1, lsB);
            } else {    // kt == tiB
                tile_step<true >(kf, vf, qfB, j0, il, hi, i0B + il, bconst, slope2, oB0, oB1, lsB);
            }
            __builtin_amdgcn_s_setprio(0);
        }
        __syncthreads();    // readers done with cur + next-stage loads drained
    }
    write_tile(po, pl, sp, bh, i0A, il, hi, oA0, oA1, lsA);
    write_tile(po, pl, sp, bh, i0B, il, hi, oB0, oB1, lsB);
}

// ---------------------------------------------------------------------------
// Merge 4 splits (vectorized, 4 d's per thread); write bf16 [b, n, h*64+d].
// ---------------------------------------------------------------------------
__global__ __launch_bounds__(256) void merge_kernel(
    const float* __restrict__ pl, const float* __restrict__ po,
    bf16* __restrict__ attnb)
{
    int idx = blockIdx.x * 256 + threadIdx.x;   // 0 .. 16*2048*16-1
    int d = (idx & 15) * 4;
    int rbh = idx >> 4;                         // bh*2048 + n
    int n  = rbh & (NSEQ - 1);
    int bh = rbh >> 11;
    const size_t S = (size_t)(BATCH * HEADS) * NSEQ;  // 32768
    float l = 0.0f;
    float ox = 0, oy = 0, oz = 0, ow = 0;
    #pragma unroll
    for (int s = 0; s < 4; s++) {
        l += pl[(size_t)s * S + rbh];
        float4 p = *(const float4*)(po + ((size_t)s * S + rbh) * DH + d);
        ox += p.x; oy += p.y; oz += p.z; ow += p.w;
    }
    float inv = 1.0f / l;
    int b = bh >> 3, h = bh & 7;
    short4v o;
    o[0] = f2b(ox * inv); o[1] = f2b(oy * inv);
    o[2] = f2b(oz * inv); o[3] = f2b(ow * inv);
    *(short4v*)(attnb + ((size_t)(b * NSEQ + n)) * DIM + h * DH + d) = o;
}

// ---------------------------------------------------------------------------
extern "C" void kernel_launch(void* const* d_in, const int* in_sizes, int n_in,
                              void* d_out, int out_size, void* d_ws, size_t ws_size,
                              hipStream_t stream)
{
    (void)in_sizes; (void)n_in; (void)out_size; (void)ws_size;
    const float* x     = (const float*)d_in[0];
    const float* gamma = (const float*)d_in[1];
    const float* beta  = (const float*)d_in[2];
    const float* wq1   = (const float*)d_in[3];
    const float* wqd   = (const float*)d_in[4];
    const float* wk1   = (const float*)d_in[5];
    const float* wkd   = (const float*)d_in[6];
    const float* wv1   = (const float*)d_in[7];
    const float* wvd   = (const float*)d_in[8];
    const float* wout  = (const float*)d_in[9];
    float* out = (float*)d_out;
    char* base = (char*)d_ws;

    const size_t MB = 1 << 20;
    bf16*  xnb   = (bf16*)(base);                 // 4 MB
    bf16*  Wcat  = (bf16*)(base + 4 * MB);        // 1.5 MB
    bf16*  woutb = (bf16*)(base + 6 * MB);        // 0.5 MB
    bf16*  qb    = (bf16*)(base + 7 * MB);        // 4 MB
    bf16*  kb    = (bf16*)(base + 11 * MB);       // 4 MB
    bf16*  vb    = (bf16*)(base + 15 * MB);       // 4 MB
    bf16*  vtb   = (bf16*)(base + 19 * MB);       // 4 MB
    bf16*  attnb = (bf16*)(base + 23 * MB);       // 4 MB
    float* pl    = (float*)(base + 27 * MB);      // 0.5 MB
    float* ycat  = (float*)(base + 32 * MB);      // 24 MB (dead after dwconv)
    float* po    = (float*)(base + 32 * MB);      // 32 MB (overlaps ycat)

    ln_convert<<<NTOK + 2048, 128, 0, stream>>>(
        x, gamma, beta, xnb, wq1, wk1, wv1, wout, Wcat, woutb);
    gemm_bf16_nt<128><<<dim3(NPROJ / 128, NTOK / 128), 256, 0, stream>>>(
        xnb, Wcat, ycat, NPROJ, DIM);
    dwconv_kernel<<<dim3(NTOK * 128 / 256, 1, 3), 256, 0, stream>>>(
        ycat, wqd, wkd, wvd, qb, kb, vb);
    vtrans_kernel<<<dim3(NSEQ / 64, BATCH * HEADS), 256, 0, stream>>>(vb, vtb);
    attn_mfma<<<dim3(8, BATCH * HEADS, 4), 256, 0, stream>>>(qb, kb, vtb, po, pl);
    merge_kernel<<<(BATCH * HEADS * NSEQ * 16) / 256, 256, 0, stream>>>(pl, po, attnb);
    gemm_bf16_nt<64><<<dim3(DIM / 64, NTOK / 128), 256, 0, stream>>>(
        attnb, woutb, out, DIM, DIM);
}

// Round 8
// 155.971 us; speedup vs baseline: 1.0927x; 1.0927x over previous
//
#include <hip/hip_runtime.h>
#include <hip/hip_bf16.h>
#include <math.h>

#define BATCH 2
#define NSEQ 2048
#define DIM 512
#define HEADS 8
#define DH 64
#define NTOK (BATCH * NSEQ)          // 4096
#define NPROJ (3 * DIM)              // 1536

typedef short short8 __attribute__((ext_vector_type(8)));   // 8 bf16 (4 VGPR)
typedef short short4v __attribute__((ext_vector_type(4)));
typedef float f32x4 __attribute__((ext_vector_type(4)));
typedef float f32x16 __attribute__((ext_vector_type(16)));
typedef __hip_bfloat16 bf16;

static __device__ __forceinline__ short f2b(float f) {
    __hip_bfloat16 h = __float2bfloat16(f);
    return *(short*)&h;
}
static __device__ __forceinline__ float b2f(short s) {
    union { unsigned u; float f; } c;
    c.u = ((unsigned)(unsigned short)s) << 16;
    return c.f;
}

static __device__ __forceinline__ void gload_lds16(const void* g, void* l) {
    __builtin_amdgcn_global_load_lds(
        (const __attribute__((address_space(1))) unsigned int*)g,
        (__attribute__((address_space(3))) unsigned int*)l, 16, 0, 0);
}

// ---------------------------------------------------------------------------
// Fused: LayerNorm (blocks 0..4095, one row each) + weight bf16 pack
// (blocks 4096..6143). 128 threads.
// ---------------------------------------------------------------------------
__global__ __launch_bounds__(128) void ln_convert(
    const float* __restrict__ x, const float* __restrict__ gamma,
    const float* __restrict__ beta, bf16* __restrict__ xnb,
    const float* __restrict__ wq1, const float* __restrict__ wk1,
    const float* __restrict__ wv1, const float* __restrict__ wout,
    bf16* __restrict__ Wcat, bf16* __restrict__ woutb)
{
    if (blockIdx.x < NTOK) {
        int row = blockIdx.x;
        int tid = threadIdx.x;
        float4 v = ((const float4*)(x + (size_t)row * DIM))[tid];
        float s  = v.x + v.y + v.z + v.w;
        float s2 = v.x*v.x + v.y*v.y + v.z*v.z + v.w*v.w;
        #pragma unroll
        for (int off = 32; off > 0; off >>= 1) {
            s  += __shfl_down(s,  off);
            s2 += __shfl_down(s2, off);
        }
        __shared__ float red[4];
        if ((tid & 63) == 0) { red[(tid >> 6) * 2] = s; red[(tid >> 6) * 2 + 1] = s2; }
        __syncthreads();
        float S  = red[0] + red[2];
        float S2 = red[1] + red[3];
        float mu  = S * (1.0f / DIM);
        float var = S2 * (1.0f / DIM) - mu * mu;
        float inv = rsqrtf(var + 1e-5f);
        float4 g  = ((const float4*)gamma)[tid];
        float4 be = ((const float4*)beta)[tid];
        short4v o;
        o[0] = f2b((v.x - mu) * inv * g.x + be.x);
        o[1] = f2b((v.y - mu) * inv * g.y + be.y);
        o[2] = f2b((v.z - mu) * inv * g.z + be.z);
        o[3] = f2b((v.w - mu) * inv * g.w + be.w);
        ((short4v*)(xnb + (size_t)row * DIM))[tid] = o;
    } else {
        int i4 = (blockIdx.x - NTOK) * 128 + threadIdx.x;   // 0 .. 262143
        int base = i4 * 4;
        int which = base >> 18;                 // 0..3 (256K elements each)
        int e = base & 262143;
        const float* src = which == 0 ? wq1 : which == 1 ? wk1 : which == 2 ? wv1 : wout;
        float4 v = *(const float4*)(src + e);
        bf16* dst = (which < 3) ? (Wcat + ((size_t)which << 18) + e) : (woutb + e);
        short4v o;
        o[0] = f2b(v.x); o[1] = f2b(v.y); o[2] = f2b(v.z); o[3] = f2b(v.w);
        *(short4v*)dst = o;
    }
}

// ---------------------------------------------------------------------------
// C[m, n] = sum_k A[m, k] * W[n, k]   (bf16 in, OUTT out)
// 128xBN tile, BK=64, 4 waves, 16x16x32 MFMA, 2-phase double-buffered
// global_load_lds pipeline (issue next tile before computing current).
// ---------------------------------------------------------------------------
template<int BN, typename OUTT>
__global__ __launch_bounds__(256) void gemm_bf16_nt(
    const bf16* __restrict__ A, const bf16* __restrict__ W,
    OUTT* __restrict__ C, int N, int K)
{
    constexpr int BITS = BN / 32;            // B-stage iterations (and n-frags)
    __shared__ bf16 As[2][128 * 64];
    __shared__ bf16 Bs[2][BN * 64];
    int tid = threadIdx.x;
    int m0 = blockIdx.y * 128, n0 = blockIdx.x * BN;
    int lane = tid & 63;
    int w = tid >> 6;
    int wm = (w >> 1) * 64, wn = (w & 1) * (BN / 2);
    int l15 = lane & 15, l4 = lane >> 4;
    f32x4 acc[4][BITS] = {};

    auto stage = [&](int b, int k0) {
        #pragma unroll
        for (int it = 0; it < 4; it++) {
            int s = it * 256 + tid;
            int row = s >> 3, cs = s & 7;
            gload_lds16(A + (size_t)(m0 + row) * K + k0 + cs * 8, &As[b][s * 8]);
        }
        #pragma unroll
        for (int it = 0; it < BITS; it++) {
            int s = it * 256 + tid;
            int row = s >> 3, cs = s & 7;
            gload_lds16(W + (size_t)(n0 + row) * K + k0 + cs * 8, &Bs[b][s * 8]);
        }
    };

    int NT = K / 64;
    stage(0, 0);
    __syncthreads();
    for (int t = 0; t < NT; ++t) {
        int cur = t & 1;
        if (t + 1 < NT) stage(cur ^ 1, (t + 1) * 64);   // issue-early: overlaps MFMA below
        #pragma unroll
        for (int kk = 0; kk < 64; kk += 32) {
            short8 af[4], bfr[BITS];
            #pragma unroll
            for (int m = 0; m < 4; m++)
                af[m] = *(const short8*)(&As[cur][(wm + m * 16 + l15) * 64 + kk + l4 * 8]);
            #pragma unroll
            for (int n = 0; n < BITS; n++)
                bfr[n] = *(const short8*)(&Bs[cur][(wn + n * 16 + l15) * 64 + kk + l4 * 8]);
            #pragma unroll
            for (int m = 0; m < 4; m++)
                #pragma unroll
                for (int n = 0; n < BITS; n++)
                    acc[m][n] = __builtin_amdgcn_mfma_f32_16x16x32_bf16(
                        af[m], bfr[n], acc[m][n], 0, 0, 0);
        }
        __syncthreads();   // drains next-tile loads (mostly landed under MFMA)
    }
    #pragma unroll
    for (int m = 0; m < 4; m++)
        #pragma unroll
        for (int n = 0; n < BITS; n++) {
            int row = m0 + wm + m * 16 + l4 * 4;
            int col = n0 + wn + n * 16 + l15;
            #pragma unroll
            for (int r = 0; r < 4; r++) {
                float val = acc[m][n][r];
                if constexpr (sizeof(OUTT) == 2)
                    ((bf16*)C)[(size_t)(row + r) * N + col] = __float2bfloat16(val);
                else
                    ((float*)C)[(size_t)(row + r) * N + col] = val;
            }
        }
}

// ---------------------------------------------------------------------------
// Depthwise causal conv (kernel 3) + head split (+ q scale).
// Reads ycat bf16 [4096][1536] (8 ch/thread); dst layout [b,h,n,d] bf16.
// ---------------------------------------------------------------------------
__global__ __launch_bounds__(256) void dwconv_kernel(
    const bf16* __restrict__ ycat,
    const float* __restrict__ wqd, const float* __restrict__ wkd, const float* __restrict__ wvd,
    bf16* __restrict__ q, bf16* __restrict__ k, bf16* __restrict__ v)
{
    int which = blockIdx.z;
    const float* wd = which == 0 ? wqd : which == 1 ? wkd : wvd;
    bf16* dst       = which == 0 ? q   : which == 1 ? k   : v;
    float scale     = which == 0 ? 0.125f : 1.0f;   // DH^-0.5 = 1/8
    int idx = blockIdx.x * 256 + threadIdx.x;       // 0 .. NTOK*64-1
    int e8 = (idx & 63) * 8;
    int t  = idx >> 6;
    int n  = t & (NSEQ - 1);
    const bf16* y = ycat + (size_t)t * NPROJ + which * DIM + e8;
    short8 zero = {0,0,0,0,0,0,0,0};
    short8 y0 = *(const short8*)y;
    short8 y1 = (n >= 1) ? *(const short8*)(y - NPROJ) : zero;
    short8 y2 = (n >= 2) ? *(const short8*)(y - 2 * NPROJ) : zero;
    const float* wf = wd + e8 * 3;                  // 24 consecutive floats
    short8 o;
    #pragma unroll
    for (int j = 0; j < 8; j++) {
        float r = wf[3*j] * b2f(y2[j]) + wf[3*j+1] * b2f(y1[j]) + wf[3*j+2] * b2f(y0[j]);
        o[j] = f2b(r * scale);
    }
    int b = t >> 11;
    int h = e8 >> 6, d = e8 & 63;
    *(short8*)(dst + (((size_t)(b * HEADS + h)) * NSEQ + n) * DH + d) = o;
}

// ---------------------------------------------------------------------------
// V transpose: v[bh][n][d] -> vT[bh][d][n]  (bf16). 64x64 tiles via LDS.
// ---------------------------------------------------------------------------
__global__ __launch_bounds__(256) void vtrans_kernel(
    const bf16* __restrict__ v, bf16* __restrict__ vT)
{
    __shared__ unsigned short L[64][72];
    int bh = blockIdx.y;
    int n0 = blockIdx.x * 64;
    int tid = threadIdx.x;
    const unsigned short* src = (const unsigned short*)v + ((size_t)bh * NSEQ + n0) * DH;
    #pragma unroll
    for (int it = 0; it < 2; it++) {
        int idx = it * 256 + tid;
        int r = idx >> 3, c = (idx & 7) * 8;
        *(short8*)&L[r][c] = *(const short8*)(src + (size_t)r * DH + c);
    }
    __syncthreads();
    unsigned short* dst = (unsigned short*)vT + (size_t)bh * DH * NSEQ + n0;
    #pragma unroll
    for (int it = 0; it < 2; it++) {
        int idx = it * 256 + tid;
        int d = idx >> 3, c8 = (idx & 7) * 8;
        short8 o;
        #pragma unroll
        for (int t = 0; t < 8; t++) o[t] = (short)L[c8 + t][d];
        *(short8*)(dst + (size_t)d * NSEQ + c8) = o;
    }
}

// ---------------------------------------------------------------------------
// MFMA flash attention (round-6 structure: per-wave dual query-tile, 4-way
// key split, K prefetch, ALiBi window cutoff). Partials po in bf16.
// ---------------------------------------------------------------------------
struct Kf { short8 k[4]; };
struct Vf { short8 v0[2]; short8 v1[2]; };

__device__ __forceinline__ Kf load_k(const bf16* __restrict__ Kb, int j0, int il, int hi) {
    Kf r;
    const short8* krow = (const short8*)(Kb + (size_t)(j0 + il) * DH);
    #pragma unroll
    for (int c = 0; c < 4; c++) r.k[c] = krow[2 * c + hi];
    return r;
}

__device__ __forceinline__ Vf load_v(const unsigned short* __restrict__ vt, int j0, int il, int hi) {
    Vf r;
    #pragma unroll
    for (int jc = 0; jc < 2; jc++) {
        r.v0[jc] = *(const short8*)(vt + (size_t)il * NSEQ + j0 + jc * 16 + hi * 8);
        r.v1[jc] = *(const short8*)(vt + (size_t)(32 + il) * NSEQ + j0 + jc * 16 + hi * 8);
    }
    return r;
}

template<bool MASKED>
__device__ __forceinline__ void tile_step(
    const Kf& kf, const Vf& vf, const short8* qf,
    int j0, int il, int hi, int i_global,
    const float* bconst, float slope2,
    f32x16& o0, f32x16& o1, float& lsum)
{
    f32x16 st = {};
    #pragma unroll
    for (int c = 0; c < 4; c++)
        st = __builtin_amdgcn_mfma_f32_32x32x16_bf16(kf.k[c], qf[c], st, 0, 0, 0);
    float sdb = slope2 * (float)(j0 - i_global);
    float p[16];
    #pragma unroll
    for (int r = 0; r < 16; r++) {
        float e = fmaf(st[r], 1.4426950408889634f, sdb + bconst[r]);
        float pr = exp2f(e);
        if (MASKED) {
            int jl = (r & 3) + 8 * (r >> 2) + 4 * hi;
            pr = (jl <= il) ? pr : 0.0f;
        }
        p[r] = pr;
        lsum += pr;
    }
    unsigned w[8];
    #pragma unroll
    for (int g = 0; g < 4; g++) {
        asm("v_cvt_pk_bf16_f32 %0, %1, %2" : "=v"(w[2*g])   : "v"(p[4*g]),   "v"(p[4*g+1]));
        asm("v_cvt_pk_bf16_f32 %0, %1, %2" : "=v"(w[2*g+1]) : "v"(p[4*g+2]), "v"(p[4*g+3]));
    }
    #pragma unroll
    for (int jc = 0; jc < 2; jc++) {
        unsigned x0 = w[4*jc], x1 = w[4*jc+1], y0 = w[4*jc+2], y1 = w[4*jc+3];
        asm("v_permlane32_swap_b32 %0, %1" : "+v"(x0), "+v"(y0));
        asm("v_permlane32_swap_b32 %0, %1" : "+v"(x1), "+v"(y1));
        union { unsigned u[4]; short8 s; } pa;
        pa.u[0] = x0; pa.u[1] = x1; pa.u[2] = y0; pa.u[3] = y1;
        o0 = __builtin_amdgcn_mfma_f32_32x32x16_bf16(pa.s, vf.v0[jc], o0, 0, 0, 0);
        o1 = __builtin_amdgcn_mfma_f32_32x32x16_bf16(pa.s, vf.v1[jc], o1, 0, 0, 0);
    }
}

__device__ __forceinline__ void write_tile(
    bf16* __restrict__ po, float* __restrict__ pl,
    int sp, int bh, int i0, int il, int hi,
    const f32x16& o0, const f32x16& o1, float lsum)
{
    float ltot = lsum + __shfl_xor(lsum, 32);
    size_t pbase = ((size_t)sp * (BATCH * HEADS) + bh) * NSEQ + i0;
    if (hi == 0) pl[pbase + il] = ltot;
    bf16* pop = po + pbase * DH;
    #pragma unroll
    for (int r = 0; r < 16; r++) {
        int irow = (r & 3) + 8 * (r >> 2) + 4 * hi;
        pop[(size_t)irow * DH + il]      = __float2bfloat16(o0[r]);
        pop[(size_t)irow * DH + 32 + il] = __float2bfloat16(o1[r]);
    }
}

__global__ __launch_bounds__(64) void attn_mfma(
    const bf16* __restrict__ Q, const bf16* __restrict__ K,
    const bf16* __restrict__ VT, bf16* __restrict__ po, float* __restrict__ pl)
{
    int t  = 31 - blockIdx.x;                       // heavy tiles dispatch first
    int bh = blockIdx.y;
    int sp = blockIdx.z;                            // key-tile residue 0..3
    int h = bh & (HEADS - 1);
    int tiA = 2 * t, tiB = 2 * t + 1;
    int i0A = tiA * 32, i0B = i0A + 32;
    int lane = threadIdx.x;
    int il = lane & 31, hi = lane >> 5;
    float slope2 = exp2f(-(float)(h + 1)) * 1.4426950408889634f;
    float bconst[16];
    #pragma unroll
    for (int r = 0; r < 16; r++) {
        int jl = (r & 3) + 8 * (r >> 2) + 4 * hi;
        bconst[r] = slope2 * (float)jl;
    }
    const bf16* Qb = Q + (size_t)bh * NSEQ * DH;
    const bf16* Kb = K + (size_t)bh * NSEQ * DH;
    const unsigned short* vt = (const unsigned short*)(VT + (size_t)bh * DH * NSEQ);
    short8 qfA[4], qfB[4];
    {
        const short8* qra = (const short8*)(Qb + (size_t)(i0A + il) * DH);
        const short8* qrb = (const short8*)(Qb + (size_t)(i0B + il) * DH);
        #pragma unroll
        for (int c = 0; c < 4; c++) { qfA[c] = qra[2 * c + hi]; qfB[c] = qrb[2 * c + hi]; }
    }
    f32x16 oA0 = {}, oA1 = {}, oB0 = {}, oB1 = {};
    float lsA = 0.0f, lsB = 0.0f;

    // ALiBi window: keys with (i - j) > Wn are negligible (< e^-20 relative).
    int Wn = 20 << (h + 1);
    int lo = (i0A - Wn) >> 5;                       // first useful kt (floor)
    int kt0 = sp;
    if (lo > sp) kt0 = sp + (((lo - sp) + 3) & ~3); // round up, keep kt0 % 4 == sp

    Kf kcur = load_k(Kb, kt0 * 32, il, hi);         // kt0*32 <= i0A < NSEQ: valid
    for (int kt = kt0; kt <= tiB; kt += 4) {
        int j0 = kt * 32;
        Vf vf = load_v(vt, j0, il, hi);
        int jn = (kt + 4 <= tiB) ? (kt + 4) * 32 : j0;
        Kf knxt = load_k(Kb, jn, il, hi);
        if (kt < tiA) {
            tile_step<false>(kcur, vf, qfA, j0, il, hi, i0A + il, bconst, slope2, oA0, oA1, lsA);
            tile_step<false>(kcur, vf, qfB, j0, il, hi, i0B + il, bconst, slope2, oB0, oB1, lsB);
        } else if (kt == tiA) {
            tile_step<true >(kcur, vf, qfA, j0, il, hi, i0A + il, bconst, slope2, oA0, oA1, lsA);
            tile_step<false>(kcur, vf, qfB, j0, il, hi, i0B + il, bconst, slope2, oB0, oB1, lsB);
        } else {    // kt == tiB
            tile_step<true >(kcur, vf, qfB, j0, il, hi, i0B + il, bconst, slope2, oB0, oB1, lsB);
        }
        kcur = knxt;
    }
    write_tile(po, pl, sp, bh, i0A, il, hi, oA0, oA1, lsA);
    write_tile(po, pl, sp, bh, i0B, il, hi, oB0, oB1, lsB);
}

// ---------------------------------------------------------------------------
// Merge 4 splits (bf16 partials, 4 d's per thread); write bf16 [b, n, h*64+d].
// ---------------------------------------------------------------------------
__global__ __launch_bounds__(256) void merge_kernel(
    const float* __restrict__ pl, const bf16* __restrict__ po,
    bf16* __restrict__ attnb)
{
    int idx = blockIdx.x * 256 + threadIdx.x;   // 0 .. 16*2048*16-1
    int d = (idx & 15) * 4;
    int rbh = idx >> 4;                         // bh*2048 + n
    int n  = rbh & (NSEQ - 1);
    int bh = rbh >> 11;
    const size_t S = (size_t)(BATCH * HEADS) * NSEQ;  // 32768
    float l = 0.0f;
    float ox = 0, oy = 0, oz = 0, ow = 0;
    #pragma unroll
    for (int s = 0; s < 4; s++) {
        l += pl[(size_t)s * S + rbh];
        short4v p = *(const short4v*)(po + ((size_t)s * S + rbh) * DH + d);
        ox += b2f(p[0]); oy += b2f(p[1]); oz += b2f(p[2]); ow += b2f(p[3]);
    }
    float inv = 1.0f / l;
    int b = bh >> 3, h = bh & 7;
    short4v o;
    o[0] = f2b(ox * inv); o[1] = f2b(oy * inv);
    o[2] = f2b(oz * inv); o[3] = f2b(ow * inv);
    *(short4v*)(attnb + ((size_t)(b * NSEQ + n)) * DIM + h * DH + d) = o;
}

// ---------------------------------------------------------------------------
extern "C" void kernel_launch(void* const* d_in, const int* in_sizes, int n_in,
                              void* d_out, int out_size, void* d_ws, size_t ws_size,
                              hipStream_t stream)
{
    (void)in_sizes; (void)n_in; (void)out_size; (void)ws_size;
    const float* x     = (const float*)d_in[0];
    const float* gamma = (const float*)d_in[1];
    const float* beta  = (const float*)d_in[2];
    const float* wq1   = (const float*)d_in[3];
    const float* wqd   = (const float*)d_in[4];
    const float* wk1   = (const float*)d_in[5];
    const float* wkd   = (const float*)d_in[6];
    const float* wv1   = (const float*)d_in[7];
    const float* wvd   = (const float*)d_in[8];
    const float* wout  = (const float*)d_in[9];
    float* out = (float*)d_out;
    char* base = (char*)d_ws;

    const size_t MB = 1 << 20;
    bf16*  xnb   = (bf16*)(base);                 // 4 MB
    bf16*  Wcat  = (bf16*)(base + 4 * MB);        // 1.5 MB
    bf16*  woutb = (bf16*)(base + 6 * MB);        // 0.5 MB
    bf16*  qb    = (bf16*)(base + 7 * MB);        // 4 MB
    bf16*  kb    = (bf16*)(base + 11 * MB);       // 4 MB
    bf16*  vb    = (bf16*)(base + 15 * MB);       // 4 MB
    bf16*  vtb   = (bf16*)(base + 19 * MB);       // 4 MB
    bf16*  attnb = (bf16*)(base + 23 * MB);       // 4 MB
    float* pl    = (float*)(base + 27 * MB);      // 0.5 MB
    bf16*  ycat  = (bf16*)(base + 32 * MB);       // 12 MB (dead after dwconv)
    bf16*  po    = (bf16*)(base + 32 * MB);       // 16 MB (overlaps ycat)

    ln_convert<<<NTOK + 2048, 128, 0, stream>>>(
        x, gamma, beta, xnb, wq1, wk1, wv1, wout, Wcat, woutb);
    gemm_bf16_nt<128, bf16><<<dim3(NPROJ / 128, NTOK / 128), 256, 0, stream>>>(
        xnb, Wcat, ycat, NPROJ, DIM);
    dwconv_kernel<<<dim3(NTOK * 64 / 256, 1, 3), 256, 0, stream>>>(
        ycat, wqd, wkd, wvd, qb, kb, vb);
    vtrans_kernel<<<dim3(NSEQ / 64, BATCH * HEADS), 256, 0, stream>>>(vb, vtb);
    attn_mfma<<<dim3(32, BATCH * HEADS, 4), 64, 0, stream>>>(qb, kb, vtb, po, pl);
    merge_kernel<<<(BATCH * HEADS * NSEQ * 16) / 256, 256, 0, stream>>>(pl, po, attnb);
    gemm_bf16_nt<64, float><<<dim3(DIM / 64, NTOK / 128), 256, 0, stream>>>(
        attnb, woutb, out, DIM, DIM);
}